// Round 13
// baseline (124.972 us; speedup 1.0000x reference)
//
#include <hip/hip_runtime.h>
#include <hip/hip_bf16.h>
#include <hip/hip_cooperative_groups.h>

namespace cg = cooperative_groups;

#define NN 96
// tanh(x) = 1 - 2/(exp2(C*x)+1), C = 2*log2(e)
#define C_TANH 2.8853900817779268f

typedef __attribute__((ext_vector_type(4))) float    f32x4;
typedef __attribute__((ext_vector_type(2))) float    f32x2;
typedef __attribute__((ext_vector_type(8))) short    short8;
typedef __attribute__((ext_vector_type(8))) _Float16 half8;

static __device__ inline unsigned int cvt_pk_bf16(float lo, float hi) {
    unsigned int r;
    asm("v_cvt_pk_bf16_f32 %0, %1, %2" : "=v"(r) : "v"(lo), "v"(hi));
    return r;
}

// ===========================================================================
// FUSED cooperative kernel: 256 blocks x 512 thr -> needs only 1 block/CU
// co-resident (58KB LDS < 64KB/wg) -- robust under any occupancy accounting.
// Phase A: gemm 96M x 128N per block (32 m-tiles x 8 n-tiles; xcd=bid&7 owns
//   m-rows [xcd*384,+384)); 8 waves, wave = 96M x 16N (acc[6]); T14 RA/RB.
// grid.sync();
// Phase B: 2 tiles of 24i x 24j per block (a_s staged once, h_s restaged);
//   split-k=8 (kq=wave, w2 scalar s_load); lane = 3i x 3j; pair-rcp.
// ===========================================================================
__global__ __launch_bounds__(512, 2) void fused_kernel(
        const float* __restrict__ X, const float* __restrict__ W1,
        const float* __restrict__ b1, const float* __restrict__ w2,
        const float* __restrict__ b2, _Float16* __restrict__ Ea,
        _Float16* __restrict__ Eh, float* __restrict__ out) {
    __shared__ __align__(16) char smem[65280];

    int bid = blockIdx.x;                // 256
    int tid = threadIdx.x;               // 512
    int xcd = bid & 7;
    int sub = bid >> 3;                  // 0..31
    int w   = tid >> 6;                  // 0..7
    int l   = tid & 63;

    // ================= Phase A =================
    {
        unsigned short* lds = (unsigned short*)smem;   // [2][7168] halves
        int mloc = sub & 3;
        int nq   = sub >> 2;             // 0..7
        int mb   = xcd * 384 + mloc * 96;
        int nb   = nq * 128;

        // chunk map: 896 16B-chunks/k-step (384 A + 512 B); thread: chunk tid
        // (+ chunk 512+tid if tid<384). Wave-uniform split at wave 6.
        const float* csrc0;
        const float* csrc1 = X;
        int cdst0, cdst1 = 0;
        if (tid < 384) {
            int ar = tid >> 2, g = tid & 3;
            csrc0 = X + (mb + ar) * 512 + g * 8;
            cdst0 = ar * 32 + ((g * 8) ^ ((ar & 3) << 3));
            int br = (128 + tid) >> 2, g2 = tid & 3;
            int nrow = nb + br;
            csrc1 = W1 + (nrow & 511) * 1024 + ((nrow >> 9) << 9) + g2 * 8;
            cdst1 = (96 + br) * 32 + ((g2 * 8) ^ ((br & 3) << 3));
        } else {
            int br = (tid - 384) >> 2, g = (tid - 384) & 3;
            int nrow = nb + br;
            csrc0 = W1 + (nrow & 511) * 1024 + ((nrow >> 9) << 9) + g * 8;
            cdst0 = (96 + br) * 32 + ((g * 8) ^ ((br & 3) << 3));
        }

        struct R2 { f32x4 a0, a1, b0, b1; };
        R2 RA, RB;

#define LOADR(R, k0)                                                          \
        {                                                                     \
            R.a0 = *(const f32x4*)(csrc0 + (k0));                             \
            R.a1 = *(const f32x4*)(csrc0 + (k0) + 4);                         \
            if (tid < 384) {                                                  \
                R.b0 = *(const f32x4*)(csrc1 + (k0));                         \
                R.b1 = *(const f32x4*)(csrc1 + (k0) + 4);                     \
            }                                                                 \
        }
#define WRITER(R, buf)                                                        \
        {                                                                     \
            uint4 u;                                                          \
            u.x = cvt_pk_bf16(R.a0[0], R.a0[1]); u.y = cvt_pk_bf16(R.a0[2], R.a0[3]); \
            u.z = cvt_pk_bf16(R.a1[0], R.a1[1]); u.w = cvt_pk_bf16(R.a1[2], R.a1[3]); \
            *(uint4*)(lds + (buf) * 7168 + cdst0) = u;                        \
            if (tid < 384) {                                                  \
                uint4 v;                                                      \
                v.x = cvt_pk_bf16(R.b0[0], R.b0[1]); v.y = cvt_pk_bf16(R.b0[2], R.b0[3]); \
                v.z = cvt_pk_bf16(R.b1[0], R.b1[1]); v.w = cvt_pk_bf16(R.b1[2], R.b1[3]); \
                *(uint4*)(lds + (buf) * 7168 + cdst1) = v;                    \
            }                                                                 \
        }

        int lr    = l & 15;
        int koffs = ((l >> 4) * 8) ^ ((lr & 3) << 3);
        int boff  = (96 + 16 * w + lr) * 32 + koffs;

        f32x4 acc[6] = {};

#define COMPUTE(cur)                                                          \
        {                                                                     \
            const unsigned short* base = lds + (cur) * 7168;                  \
            short8 bfr = *(const short8*)(base + boff);                       \
            _Pragma("unroll")                                                 \
            for (int rf = 0; rf < 6; ++rf) {                                  \
                short8 afr = *(const short8*)(base + (16 * rf + lr) * 32 + koffs); \
                acc[rf] = __builtin_amdgcn_mfma_f32_16x16x32_bf16(afr, bfr,   \
                                                              acc[rf], 0, 0, 0); \
            }                                                                 \
        }

        LOADR(RA, 0)
        WRITER(RA, 0)
        LOADR(RB, 32)
        __syncthreads();
#pragma unroll 1
        for (int kk = 0; kk < 7; ++kk) {
            LOADR(RA, (2 * kk + 2) * 32)
            COMPUTE(0)
            WRITER(RB, 1)
            __syncthreads();
            LOADR(RB, (2 * kk + 3) * 32)
            COMPUTE(1)
            WRITER(RA, 0)
            __syncthreads();
        }
        COMPUTE(0)
        WRITER(RB, 1)
        __syncthreads();
        COMPUTE(1)
#undef LOADR
#undef WRITER
#undef COMPUTE

        int r0 = (l >> 4) * 4;
        bool isB = (nb >= 512);
        int col  = (nb & 511) + 16 * w + lr;    // uniform wave-col band
        float bias = isB ? b1[col] : 0.0f;
        _Float16* dst = isB ? Eh : Ea;
#pragma unroll
        for (int rf = 0; rf < 6; ++rf)
#pragma unroll
            for (int q = 0; q < 4; ++q) {
                int m = mb + 16 * rf + r0 + q;
                float arg = (acc[rf][q] + bias) * C_TANH;
                dst[m * 512 + col] = (_Float16)exp2f(arg);
            }
    }

    __threadfence();
    cg::this_grid().sync();

    // ================= Phase B =================
    {
        _Float16* a_s = (_Float16*)smem;                 // 24 rows = 24KB
        _Float16* h_s = (_Float16*)(smem + 24576);       // 24 rows = 24KB
        float*    red = (float*)(smem + 49152);          // [7][64][9] = 16128B

        int bloc = sub >> 3;             // 0..3
        int rem  = sub & 7;
        int it   = rem >> 1;             // 0..3
        int jp   = rem & 1;              // jt = 2jp + jj
        int b    = xcd * 4 + bloc;

        const _Float16* asrc = Ea + (b * NN + it * 24) * 512;
#pragma unroll
        for (int p = 0; p < 3; ++p) {    // stage a: 24x64 = 1536 chunks
            int idx = tid + p * 512;
            int row = idx >> 6, c = idx & 63, cs = c ^ (row & 7);
            *(f32x4*)(a_s + row * 512 + cs * 8) =
                *(const f32x4*)(asrc + row * 512 + c * 8);
        }

        int kq = __builtin_amdgcn_readfirstlane(w);   // SGPR 0..7
        int pi = l >> 3;                 // rows 3pi..3pi+2
        int pj = l & 7;                  // cols 3pj..3pj+2
        const float* wp = w2 + kq * 64;  // uniform -> s_load
        float Sv = 0.f;                  // wave 0 keeps across jj

        const _Float16* pa[3];
        int sa[3];
#pragma unroll
        for (int d = 0; d < 3; ++d) {
            int ra = 3 * pi + d;
            pa[d] = a_s + ra * 512 + kq * 64;
            sa[d] = ra & 7;
        }

#define FPROC(av, hv, acc)                                                    \
        {                                                                     \
            float s0 = __builtin_fmaf((float)av[0], (float)hv[0], 1.0f);      \
            float s1 = __builtin_fmaf((float)av[1], (float)hv[1], 1.0f);      \
            float s2 = __builtin_fmaf((float)av[2], (float)hv[2], 1.0f);      \
            float s3 = __builtin_fmaf((float)av[3], (float)hv[3], 1.0f);      \
            float s4 = __builtin_fmaf((float)av[4], (float)hv[4], 1.0f);      \
            float s5 = __builtin_fmaf((float)av[5], (float)hv[5], 1.0f);      \
            float s6 = __builtin_fmaf((float)av[6], (float)hv[6], 1.0f);      \
            float s7 = __builtin_fmaf((float)av[7], (float)hv[7], 1.0f);      \
            float n0 = __builtin_fmaf(wv1, s0, wv0 * s1);                     \
            float n1 = __builtin_fmaf(wv3, s2, wv2 * s3);                     \
            float n2 = __builtin_fmaf(wv5, s4, wv4 * s5);                     \
            float n3 = __builtin_fmaf(wv7, s6, wv6 * s7);                     \
            acc = __builtin_fmaf(n0, __builtin_amdgcn_rcpf(s0 * s1), acc);    \
            acc = __builtin_fmaf(n1, __builtin_amdgcn_rcpf(s2 * s3), acc);    \
            acc = __builtin_fmaf(n2, __builtin_amdgcn_rcpf(s4 * s5), acc);    \
            acc = __builtin_fmaf(n3, __builtin_amdgcn_rcpf(s6 * s7), acc);    \
        }

#pragma unroll 1
        for (int jj = 0; jj < 2; ++jj) {
            int jt = jp * 2 + jj;
            const _Float16* hsrc = Eh + (b * NN + jt * 24) * 512;
#pragma unroll
            for (int p = 0; p < 3; ++p) {
                int idx = tid + p * 512;
                int row = idx >> 6, c = idx & 63, cs = c ^ (row & 7);
                *(f32x4*)(h_s + row * 512 + cs * 8) =
                    *(const f32x4*)(hsrc + row * 512 + c * 8);
            }
            __syncthreads();

            float acc[3][3] = {};
            const _Float16* ph[3];
            int sh[3];
#pragma unroll
            for (int d = 0; d < 3; ++d) {
                int rh = 3 * pj + d;
                ph[d] = h_s + rh * 512 + kq * 64;
                sh[d] = rh & 7;
            }

#pragma unroll
            for (int c = 0; c < 8; ++c) {
                half8 av[3], hv[3];
#pragma unroll
                for (int d = 0; d < 3; ++d) {
                    av[d] = *(const half8*)(pa[d] + ((c ^ sa[d]) << 3));
                    hv[d] = *(const half8*)(ph[d] + ((c ^ sh[d]) << 3));
                }
                f32x4 wlo = *(const f32x4*)(wp + c * 8);
                f32x4 whi = *(const f32x4*)(wp + c * 8 + 4);
                float wv0 = wlo[0], wv1 = wlo[1], wv2 = wlo[2], wv3 = wlo[3];
                float wv4 = whi[0], wv5 = whi[1], wv6 = whi[2], wv7 = whi[3];
#pragma unroll
                for (int di = 0; di < 3; ++di)
#pragma unroll
                    for (int dj = 0; dj < 3; ++dj)
                        FPROC(av[di], hv[dj], acc[di][dj])
            }

            if (w != 0) {
                float* rp = red + ((w - 1) * 64 + l) * 9;
#pragma unroll
                for (int di = 0; di < 3; ++di)
#pragma unroll
                    for (int dj = 0; dj < 3; ++dj)
                        rp[di * 3 + dj] = acc[di][dj];
            }
            __syncthreads();

            if (w == 0) {
#pragma unroll
                for (int rr = 0; rr < 7; ++rr) {
                    const float* rp = red + (rr * 64 + l) * 9;
#pragma unroll
                    for (int di = 0; di < 3; ++di)
#pragma unroll
                        for (int dj = 0; dj < 3; ++dj)
                            acc[di][dj] += rp[di * 3 + dj];
                }
                if (jj == 0) {
                    f32x4 v0 = *(const f32x4*)(w2 + l * 8);
                    f32x4 v1 = *(const f32x4*)(w2 + l * 8 + 4);
                    float sv = (v0[0] + v0[1]) + (v0[2] + v0[3])
                             + (v1[0] + v1[1]) + (v1[2] + v1[3]);
#pragma unroll
                    for (int off = 32; off; off >>= 1) sv += __shfl_xor(sv, off, 64);
                    Sv = sv + b2[0];
                }
#pragma unroll
                for (int di = 0; di < 3; ++di) {
                    int i = it * 24 + 3 * pi + di;
                    float* op = out + (b * NN + i) * NN + jt * 24 + 3 * pj;
#pragma unroll
                    for (int dj = 0; dj < 3; ++dj)
                        op[dj] = __builtin_fmaf(-2.f, acc[di][dj], Sv);
                }
            }
            __syncthreads();             // red & h_s safe for next jj
        }
#undef FPROC
    }
}

// ===========================================================================
// FALLBACK path (R8-proven, 35.8 µs): used if cooperative launch is rejected.
// ===========================================================================
__global__ __launch_bounds__(256) void gemm_h(const float* __restrict__ X,
                                              const float* __restrict__ W1,
                                              const float* __restrict__ b1,
                                              _Float16* __restrict__ Ea,
                                              _Float16* __restrict__ Eh) {
    __shared__ unsigned short As[2][2048];
    __shared__ unsigned short Bs[2][2048];

    int bid  = blockIdx.x;
    int xcd  = bid & 7;
    int sub  = bid >> 3;
    int mloc = sub % 6;
    int nq   = sub / 6;
    int mb   = (xcd * 6 + mloc) * 64;
    int nb   = nq * 64;
    int tid = threadIdx.x;
    int w   = tid >> 6;
    int l   = tid & 63;

    int srow = tid >> 2;
    int sg   = (tid & 3) * 8;
    int scs  = sg ^ ((srow & 3) << 3);
    const float* asrc = X + (mb + srow) * 512 + sg;
    int nrow = nb + srow;
    const float* bsrc = W1 + (nrow & 511) * 1024 + ((nrow >> 9) << 9) + sg;
    unsigned short* adst = &As[0][srow * 32 + scs];
    unsigned short* bdst = &Bs[0][srow * 32 + scs];

    struct Regs { f32x4 a0, a1, b0, b4; };
    Regs RA, RB;

#define LOADR(R, k0)                                                          \
    {                                                                         \
        R.a0 = *(const f32x4*)(asrc + (k0));                                  \
        R.a1 = *(const f32x4*)(asrc + (k0) + 4);                              \
        R.b0 = *(const f32x4*)(bsrc + (k0));                                  \
        R.b4 = *(const f32x4*)(bsrc + (k0) + 4);                              \
    }
#define WRITER(R, buf)                                                        \
    {                                                                         \
        uint4 ua, ub;                                                         \
        ua.x = cvt_pk_bf16(R.a0[0], R.a0[1]); ua.y = cvt_pk_bf16(R.a0[2], R.a0[3]); \
        ua.z = cvt_pk_bf16(R.a1[0], R.a1[1]); ua.w = cvt_pk_bf16(R.a1[2], R.a1[3]); \
        ub.x = cvt_pk_bf16(R.b0[0], R.b0[1]); ub.y = cvt_pk_bf16(R.b0[2], R.b0[3]); \
        ub.z = cvt_pk_bf16(R.b4[0], R.b4[1]); ub.w = cvt_pk_bf16(R.b4[2], R.b4[3]); \
        *(uint4*)(adst + (buf) * 2048) = ua;                                  \
        *(uint4*)(bdst + (buf) * 2048) = ub;                                  \
    }

    int lr    = l & 15;
    int koffs = ((l >> 4) * 8) ^ ((lr & 3) << 3);
    int aoff  = (16 * w + lr) * 32 + koffs;
    int boff0 = lr * 32 + koffs;

    f32x4 acc[4] = {};

#define COMPUTE(cur)                                                          \
    {                                                                         \
        short8 afr = *(const short8*)(&As[cur][aoff]);                        \
        short8 bfr[4];                                                        \
        _Pragma("unroll")                                                     \
        for (int t = 0; t < 4; ++t)                                           \
            bfr[t] = *(const short8*)(&Bs[cur][boff0 + t * 512]);             \
        _Pragma("unroll")                                                     \
        for (int t = 0; t < 4; ++t)                                           \
            acc[t] = __builtin_amdgcn_mfma_f32_16x16x32_bf16(afr, bfr[t],     \
                                                             acc[t], 0, 0, 0);\
    }

    LOADR(RA, 0)
    WRITER(RA, 0)
    LOADR(RB, 32)
    __syncthreads();
#pragma unroll 1
    for (int kk = 0; kk < 7; ++kk) {
        LOADR(RA, (2 * kk + 2) * 32)
        COMPUTE(0)
        WRITER(RB, 1)
        __syncthreads();
        LOADR(RB, (2 * kk + 3) * 32)
        COMPUTE(1)
        WRITER(RA, 0)
        __syncthreads();
    }
    COMPUTE(0)
    WRITER(RB, 1)
    __syncthreads();
    COMPUTE(1)
#undef LOADR
#undef WRITER
#undef COMPUTE

    int r0 = (l >> 4) * 4;
    bool isB = (nb >= 512);
    int colbase = nb & 511;
    _Float16* dst = isB ? Eh : Ea;
#pragma unroll
    for (int t = 0; t < 4; ++t) {
        int col = colbase + 16 * t + lr;
        float bias = isB ? b1[col] : 0.0f;
#pragma unroll
        for (int q = 0; q < 4; ++q) {
            int m = mb + 16 * w + r0 + q;
            float arg = (acc[t][q] + bias) * C_TANH;
            dst[m * 512 + col] = (_Float16)exp2f(arg);
        }
    }
}

__global__ __launch_bounds__(256) void arc_kernel(const _Float16* __restrict__ Ea,
                                                  const _Float16* __restrict__ Eh,
                                                  const float* __restrict__ w2,
                                                  const float* __restrict__ b2,
                                                  float* __restrict__ out) {
    __shared__ _Float16 a_s[16 * 512];
    __shared__ _Float16 h_s[16 * 512];
    __shared__ float    red[3][64][4];

    int bid = blockIdx.x;
    int xcd = bid & 7;
    int sub = bid >> 3;
    int b   = xcd * 4 + sub / 36;
    int r   = sub % 36;
    int it  = r / 6;
    int jt  = r % 6;
    int tid = threadIdx.x;

    const _Float16* asrc = Ea + (b * NN + it * 16) * 512;
    const _Float16* hsrc = Eh + (b * NN + jt * 16) * 512;

#pragma unroll
    for (int p = 0; p < 4; ++p) {
        int idx = tid + p * 256;
        int row = idx >> 6, c = idx & 63;
        int cs = c ^ (row & 7);
        *(f32x4*)(a_s + row * 512 + cs * 8) = *(const f32x4*)(asrc + row * 512 + c * 8);
        *(f32x4*)(h_s + row * 512 + cs * 8) = *(const f32x4*)(hsrc + row * 512 + c * 8);
    }
    __syncthreads();

    int w  = tid >> 6;
    int kq = __builtin_amdgcn_readfirstlane(w);
    int l  = tid & 63;
    int pi = l >> 3;
    int pj = l & 7;
    int r0a = pi * 2, r1a = r0a + 1;
    int r0h = pj * 2, r1h = r0h + 1;

    const _Float16* a0 = a_s + r0a * 512 + kq * 128;
    const _Float16* a1 = a_s + r1a * 512 + kq * 128;
    const _Float16* h0 = h_s + r0h * 512 + kq * 128;
    const _Float16* h1 = h_s + r1h * 512 + kq * 128;
    int sa0 = r0a & 7, sa1 = r1a & 7, sh0 = r0h & 7, sh1 = r1h & 7;
    const float* wp = w2 + kq * 128;

    float acc00 = 0.f, acc01 = 0.f, acc10 = 0.f, acc11 = 0.f;

#define PROC(av, hv, acc)                                                     \
    {                                                                         \
        float s0 = __builtin_fmaf((float)av[0], (float)hv[0], 1.0f);          \
        float s1 = __builtin_fmaf((float)av[1], (float)hv[1], 1.0f);          \
        float s2 = __builtin_fmaf((float)av[2], (float)hv[2], 1.0f);          \
        float s3 = __builtin_fmaf((float)av[3], (float)hv[3], 1.0f);          \
        float s4 = __builtin_fmaf((float)av[4], (float)hv[4], 1.0f);          \
        float s5 = __builtin_fmaf((float)av[5], (float)hv[5], 1.0f);          \
        float s6 = __builtin_fmaf((float)av[6], (float)hv[6], 1.0f);          \
        float s7 = __builtin_fmaf((float)av[7], (float)hv[7], 1.0f);          \
        float n0 = __builtin_fmaf(wv1, s0, wv0 * s1);                         \
        float n1 = __builtin_fmaf(wv3, s2, wv2 * s3);                         \
        float n2 = __builtin_fmaf(wv5, s4, wv4 * s5);                         \
        float n3 = __builtin_fmaf(wv7, s6, wv6 * s7);                         \
        acc = __builtin_fmaf(n0, __builtin_amdgcn_rcpf(s0 * s1), acc);        \
        acc = __builtin_fmaf(n1, __builtin_amdgcn_rcpf(s2 * s3), acc);        \
        acc = __builtin_fmaf(n2, __builtin_amdgcn_rcpf(s4 * s5), acc);        \
        acc = __builtin_fmaf(n3, __builtin_amdgcn_rcpf(s6 * s7), acc);        \
    }

#pragma unroll 4
    for (int c = 0; c < 16; ++c) {
        half8 av0 = *(const half8*)(a0 + ((c ^ sa0) << 3));
        half8 av1 = *(const half8*)(a1 + ((c ^ sa1) << 3));
        half8 hv0 = *(const half8*)(h0 + ((c ^ sh0) << 3));
        half8 hv1 = *(const half8*)(h1 + ((c ^ sh1) << 3));
        f32x4 wlo = *(const f32x4*)(wp + c * 8);
        f32x4 whi = *(const f32x4*)(wp + c * 8 + 4);
        float wv0 = wlo[0], wv1 = wlo[1], wv2 = wlo[2], wv3 = wlo[3];
        float wv4 = whi[0], wv5 = whi[1], wv6 = whi[2], wv7 = whi[3];
        PROC(av0, hv0, acc00)
        PROC(av0, hv1, acc01)
        PROC(av1, hv0, acc10)
        PROC(av1, hv1, acc11)
    }
#undef PROC

    if (w != 0) {
        f32x4 v = {acc00, acc01, acc10, acc11};
        *(f32x4*)(&red[w - 1][l][0]) = v;
    }
    __syncthreads();

    if (w == 0) {
#pragma unroll
        for (int rr = 0; rr < 3; ++rr) {
            f32x4 v = *(const f32x4*)(&red[rr][l][0]);
            acc00 += v[0]; acc01 += v[1]; acc10 += v[2]; acc11 += v[3];
        }
        f32x4 v0 = *(const f32x4*)(w2 + l * 8);
        f32x4 v1 = *(const f32x4*)(w2 + l * 8 + 4);
        float sv = (v0[0] + v0[1]) + (v0[2] + v0[3])
                 + (v1[0] + v1[1]) + (v1[2] + v1[3]);
#pragma unroll
        for (int off = 32; off; off >>= 1) sv += __shfl_xor(sv, off, 64);
        float Sv = sv + b2[0];

        int i0 = it * 16 + r0a;
        int j0 = jt * 16 + r0h;
        f32x2 o0 = {__builtin_fmaf(-2.f, acc00, Sv), __builtin_fmaf(-2.f, acc01, Sv)};
        f32x2 o1 = {__builtin_fmaf(-2.f, acc10, Sv), __builtin_fmaf(-2.f, acc11, Sv)};
        *(f32x2*)(out + (b * NN + i0) * NN + j0)     = o0;
        *(f32x2*)(out + (b * NN + i0 + 1) * NN + j0) = o1;
    }
}

// ---------------------------------------------------------------------------
extern "C" void kernel_launch(void* const* d_in, const int* in_sizes, int n_in,
                              void* d_out, int out_size, void* d_ws, size_t ws_size,
                              hipStream_t stream) {
    (void)in_sizes; (void)n_in; (void)out_size; (void)ws_size;

    const float* X  = (const float*)d_in[0];   // (32, 96, 512)
    const float* W1 = (const float*)d_in[1];   // (512, 1024)
    const float* b1 = (const float*)d_in[2];   // (512,)
    const float* W2 = (const float*)d_in[3];   // (1, 512)
    const float* b2 = (const float*)d_in[4];   // (1,)
    float* out = (float*)d_out;                // (32, 96, 96)

    char* ws = (char*)d_ws;
    _Float16* Ea = (_Float16*)(ws);                // 3,145,728 B
    _Float16* Eh = (_Float16*)(ws + 3145728);      // 3,145,728 B

    void* args[8] = {(void*)&X, (void*)&W1, (void*)&b1, (void*)&W2,
                     (void*)&b2, (void*)&Ea, (void*)&Eh, (void*)&out};
    hipError_t e = hipLaunchCooperativeKernel(fused_kernel, dim3(256), dim3(512),
                                              args, 0u, stream);
    if (e != hipSuccess) {
        (void)hipGetLastError();   // clear sticky error; take proven 2-kernel path
        gemm_h<<<768, 256, 0, stream>>>(X, W1, b1, Ea, Eh);
        arc_kernel<<<1152, 256, 0, stream>>>(Ea, Eh, W2, b2, out);
    }
}

// Round 16
// 122.628 us; speedup vs baseline: 1.0191x; 1.0191x over previous
//
#include <hip/hip_runtime.h>
#include <hip/hip_bf16.h>

#define NN 96
// tanh(x) = 1 - 2/(exp2(C*x)+1), C = 2*log2(e)
#define C_TANH 2.8853900817779268f

typedef __attribute__((ext_vector_type(4))) float    f32x4;
typedef __attribute__((ext_vector_type(8))) short    short8;
typedef __attribute__((ext_vector_type(8))) _Float16 half8;

static __device__ inline unsigned int cvt_pk_bf16(float lo, float hi) {
    unsigned int r;
    asm("v_cvt_pk_bf16_f32 %0, %1, %2" : "=v"(r) : "v"(lo), "v"(hi));
    return r;
}

// ===========================================================================
// Single fused producer-consumer kernel. 512 blocks x 256 thr.
// LDS 48KB -> 3 blocks/CU capacity; grid 512 <= 768 => ALL blocks co-resident
// => spin-waits cannot deadlock (every block runs its producer phase first).
//
// Block (xcd=bid&7, sub=bid>>3): b = 4*xcd + sub/16 (batch), nq = sub%16.
//  Producer: gemm tile = batch b's 96 rows x 64 N-cols [64nq, +64), K=512.
//    nq<8 -> Ea half (cols 64nq..), nq>=8 -> Eh half. Ea=fp16(2^(C*Ha)),
//    Eh=fp16(2^(C*(Hb+b1))). After epilogue: threadfence; sync; thread0
//    atomicAdd(cnt[b], 1, release, agent).
//  Consumer: spin until cnt[b]==16 (acquire, agent -> buffer_inv makes any
//    stale L1/L2 lines safe), then arc tile 24i x 24j of the SAME batch:
//    out = S - 2*sum_k w2[k]/(Ea[i,k]*Eh[j,k]+1), S = b2 + sum(w2).
//    4 waves = split-k quarters (w2 via scalar loads); lane = 3i x 3j;
//    pair-rcp; reduce via LDS aliased over a_s after the k-loop.
// cnt[] (32 ints in ws) is zeroed by a hipMemsetAsync node each launch ->
// identical work every replay.
// ===========================================================================
__global__ __launch_bounds__(256, 3) void fused_pc(
        const float* __restrict__ X, const float* __restrict__ W1,
        const float* __restrict__ b1, const float* __restrict__ w2,
        const float* __restrict__ b2, _Float16* __restrict__ Ea,
        _Float16* __restrict__ Eh, int* __restrict__ cnt,
        float* __restrict__ out) {
    __shared__ __align__(16) char smem[49152];

    int bid = blockIdx.x;                // 512 = 8 xcd * 64
    int tid = threadIdx.x;
    int xcd = bid & 7;
    int sub = bid >> 3;                  // 0..63
    int b   = 4 * xcd + (sub >> 4);      // batch 0..31
    int nq  = sub & 15;                  // gemm n-quarter 0..15
    int w   = tid >> 6;
    int l   = tid & 63;

    // ---------------- producer: gemm 96x64, k-step 64 ----------------
    {
        unsigned short* lds = (unsigned short*)smem;   // [2][160*64] halves

        // staging: 1280 16B-chunks per k-step (rows 0..95 = A, 96..159 = B);
        // 5 chunks/thread. chunk c: row=c>>3, g=c&7; slot = g ^ (row&7).
        const float* src[5];
        int dst[5];
#pragma unroll
        for (int p = 0; p < 5; ++p) {
            int c   = tid + p * 256;
            int row = c >> 3, g = c & 7;
            dst[p] = row * 64 + (g ^ (row & 7)) * 8;
            if (row < 96) {
                src[p] = X + (b * 96 + row) * 512 + g * 8;
            } else {
                int n = nq * 64 + (row - 96);
                src[p] = W1 + (n & 511) * 1024 + ((n >> 9) << 9) + g * 8;
            }
        }

        f32x4 RL[5][2];
#define LOADR(k0)                                                             \
        { _Pragma("unroll")                                                   \
          for (int p = 0; p < 5; ++p) {                                       \
              RL[p][0] = *(const f32x4*)(src[p] + (k0));                      \
              RL[p][1] = *(const f32x4*)(src[p] + (k0) + 4);                  \
          } }
#define WRITER(buf)                                                           \
        { _Pragma("unroll")                                                   \
          for (int p = 0; p < 5; ++p) {                                       \
              uint4 u;                                                        \
              u.x = cvt_pk_bf16(RL[p][0][0], RL[p][0][1]);                    \
              u.y = cvt_pk_bf16(RL[p][0][2], RL[p][0][3]);                    \
              u.z = cvt_pk_bf16(RL[p][1][0], RL[p][1][1]);                    \
              u.w = cvt_pk_bf16(RL[p][1][2], RL[p][1][3]);                    \
              *(uint4*)(lds + (buf) * 10240 + dst[p]) = u;                    \
          } }

        f32x4 acc[6] = {};
        int lr = l & 15;
        int kh = l >> 4;                 // 0..3 -> koff = kh*8

#define COMPUTE(buf)                                                          \
        { const unsigned short* base = lds + (buf) * 10240;                   \
          _Pragma("unroll")                                                   \
          for (int kk = 0; kk < 2; ++kk) {                                    \
              int kc = kk * 4 + kh;                                           \
              int rb = 96 + 16 * w + lr;                                      \
              short8 bfr = *(const short8*)(base + rb * 64 + ((kc ^ (rb & 7)) * 8)); \
              _Pragma("unroll")                                               \
              for (int rf = 0; rf < 6; ++rf) {                                \
                  int ra = 16 * rf + lr;                                      \
                  short8 afr = *(const short8*)(base + ra * 64 + ((kc ^ (ra & 7)) * 8)); \
                  acc[rf] = __builtin_amdgcn_mfma_f32_16x16x32_bf16(          \
                      afr, bfr, acc[rf], 0, 0, 0);                            \
              } } }

        LOADR(0)
        WRITER(0)
        __syncthreads();
#pragma unroll 1
        for (int k = 0; k < 7; ++k) {
            LOADR((k + 1) * 64)
            COMPUTE(k & 1)
            WRITER((k + 1) & 1)
            __syncthreads();
        }
        COMPUTE(1)
#undef LOADR
#undef WRITER
#undef COMPUTE

        // epilogue: D lane l -> row (l>>4)*4+q, col l&15 (within wave's 16)
        int r0 = (l >> 4) * 4;
        bool isB = (nq >= 8);
        int colh = (nq & 7) * 64 + 16 * w + lr;   // col within 512-half
        float bias = isB ? b1[colh] : 0.0f;
        _Float16* dstp = isB ? Eh : Ea;
#pragma unroll
        for (int rf = 0; rf < 6; ++rf)
#pragma unroll
            for (int q = 0; q < 4; ++q) {
                int m = b * 96 + 16 * rf + r0 + q;
                float arg = (acc[rf][q] + bias) * C_TANH;
                dstp[m * 512 + colh] = (_Float16)exp2f(arg);
            }
    }

    __threadfence();
    __syncthreads();
    if (tid == 0)
        __hip_atomic_fetch_add(&cnt[b], 1, __ATOMIC_RELEASE,
                               __HIP_MEMORY_SCOPE_AGENT);

    // wait for all 16 producers of this batch (incl. self)
    if (tid == 0) {
        while (__hip_atomic_load(&cnt[b], __ATOMIC_ACQUIRE,
                                 __HIP_MEMORY_SCOPE_AGENT) < 16)
            __builtin_amdgcn_s_sleep(1);
    }
    __syncthreads();

    // ---------------- consumer: arc 24i x 24j ----------------
    {
        _Float16* a_s = (_Float16*)smem;                 // 24x512 = 24KB
        _Float16* h_s = (_Float16*)(smem + 24576);       // 24x512 = 24KB

        int rem = sub & 15;
        int it  = rem >> 2;              // 0..3
        int jt  = rem & 3;               // 0..3

        const _Float16* asrc = Ea + (b * NN + it * 24) * 512;
        const _Float16* hsrc = Eh + (b * NN + jt * 24) * 512;

        // stage a: 24x64 = 1536 chunks (p 0..5); h: 1536 (p 6..11)
#pragma unroll
        for (int p = 0; p < 6; ++p) {
            int idx = tid + p * 256;
            int row = idx >> 6, c = idx & 63, cs = c ^ (row & 7);
            *(f32x4*)(a_s + row * 512 + cs * 8) =
                *(const f32x4*)(asrc + row * 512 + c * 8);
        }
#pragma unroll
        for (int p = 0; p < 6; ++p) {
            int idx = tid + p * 256;
            int row = idx >> 6, c = idx & 63, cs = c ^ (row & 7);
            *(f32x4*)(h_s + row * 512 + cs * 8) =
                *(const f32x4*)(hsrc + row * 512 + c * 8);
        }
        __syncthreads();

        int kq = __builtin_amdgcn_readfirstlane(w);   // SGPR 0..3
        int pi = l >> 3;                 // rows 3pi..3pi+2
        int pj = l & 7;                  // cols 3pj..3pj+2
        const float* wp = w2 + kq * 128; // uniform -> s_load

        const _Float16* pa[3];
        const _Float16* ph[3];
        int sa[3], sh[3];
#pragma unroll
        for (int d = 0; d < 3; ++d) {
            int ra = 3 * pi + d;
            int rh = 3 * pj + d;
            pa[d] = a_s + ra * 512 + kq * 128;
            ph[d] = h_s + rh * 512 + kq * 128;
            sa[d] = ra & 7;
            sh[d] = rh & 7;
        }

        float acc[3][3] = {};

#define FPROC(av, hv, a)                                                      \
        {                                                                     \
            float s0 = __builtin_fmaf((float)av[0], (float)hv[0], 1.0f);      \
            float s1 = __builtin_fmaf((float)av[1], (float)hv[1], 1.0f);      \
            float s2 = __builtin_fmaf((float)av[2], (float)hv[2], 1.0f);      \
            float s3 = __builtin_fmaf((float)av[3], (float)hv[3], 1.0f);      \
            float s4 = __builtin_fmaf((float)av[4], (float)hv[4], 1.0f);      \
            float s5 = __builtin_fmaf((float)av[5], (float)hv[5], 1.0f);      \
            float s6 = __builtin_fmaf((float)av[6], (float)hv[6], 1.0f);      \
            float s7 = __builtin_fmaf((float)av[7], (float)hv[7], 1.0f);      \
            float n0 = __builtin_fmaf(wv1, s0, wv0 * s1);                     \
            float n1 = __builtin_fmaf(wv3, s2, wv2 * s3);                     \
            float n2 = __builtin_fmaf(wv5, s4, wv4 * s5);                     \
            float n3 = __builtin_fmaf(wv7, s6, wv6 * s7);                     \
            a = __builtin_fmaf(n0, __builtin_amdgcn_rcpf(s0 * s1), a);        \
            a = __builtin_fmaf(n1, __builtin_amdgcn_rcpf(s2 * s3), a);        \
            a = __builtin_fmaf(n2, __builtin_amdgcn_rcpf(s4 * s5), a);        \
            a = __builtin_fmaf(n3, __builtin_amdgcn_rcpf(s6 * s7), a);        \
        }

#pragma unroll 2
        for (int c0 = 0; c0 < 16; ++c0) {
            half8 av[3], hv[3];
#pragma unroll
            for (int d = 0; d < 3; ++d) {
                av[d] = *(const half8*)(pa[d] + ((c0 ^ sa[d]) << 3));
                hv[d] = *(const half8*)(ph[d] + ((c0 ^ sh[d]) << 3));
            }
            f32x4 wlo = *(const f32x4*)(wp + c0 * 8);
            f32x4 whi = *(const f32x4*)(wp + c0 * 8 + 4);
            float wv0 = wlo[0], wv1 = wlo[1], wv2 = wlo[2], wv3 = wlo[3];
            float wv4 = whi[0], wv5 = whi[1], wv6 = whi[2], wv7 = whi[3];
#pragma unroll
            for (int di = 0; di < 3; ++di)
#pragma unroll
                for (int dj = 0; dj < 3; ++dj)
                    FPROC(av[di], hv[dj], acc[di][dj])
        }
#undef FPROC

        // cross-wave reduce; red aliases a_s (k-loop reads are done)
        float* red = (float*)smem;       // [2][64][9] = 4608 B
        __syncthreads();
        if (w >= 2) {
            float* rp = red + ((w - 2) * 64 + l) * 9;
#pragma unroll
            for (int di = 0; di < 3; ++di)
#pragma unroll
                for (int dj = 0; dj < 3; ++dj)
                    rp[di * 3 + dj] = acc[di][dj];
        }
        __syncthreads();
        if (w < 2) {
            const float* rp = red + (w * 64 + l) * 9;
#pragma unroll
            for (int di = 0; di < 3; ++di)
#pragma unroll
                for (int dj = 0; dj < 3; ++dj)
                    acc[di][dj] += rp[di * 3 + dj];
        }
        __syncthreads();
        if (w == 1) {
            float* rp = red + l * 9;
#pragma unroll
            for (int di = 0; di < 3; ++di)
#pragma unroll
                for (int dj = 0; dj < 3; ++dj)
                    rp[di * 3 + dj] = acc[di][dj];
        }
        __syncthreads();

        if (w == 0) {
            const float* rp = red + l * 9;
#pragma unroll
            for (int di = 0; di < 3; ++di)
#pragma unroll
                for (int dj = 0; dj < 3; ++dj)
                    acc[di][dj] += rp[di * 3 + dj];

            // S = b2 + sum(w2)
            f32x4 v0 = *(const f32x4*)(w2 + l * 8);
            f32x4 v1 = *(const f32x4*)(w2 + l * 8 + 4);
            float sv = (v0[0] + v0[1]) + (v0[2] + v0[3])
                     + (v1[0] + v1[1]) + (v1[2] + v1[3]);
#pragma unroll
            for (int off = 32; off; off >>= 1) sv += __shfl_xor(sv, off, 64);
            float Sv = sv + b2[0];

#pragma unroll
            for (int di = 0; di < 3; ++di) {
                int i = it * 24 + 3 * pi + di;
                float* op = out + (b * NN + i) * NN + jt * 24 + 3 * pj;
#pragma unroll
                for (int dj = 0; dj < 3; ++dj)
                    op[dj] = __builtin_fmaf(-2.f, acc[di][dj], Sv);
            }
        }
    }
}

// ---------------------------------------------------------------------------
extern "C" void kernel_launch(void* const* d_in, const int* in_sizes, int n_in,
                              void* d_out, int out_size, void* d_ws, size_t ws_size,
                              hipStream_t stream) {
    (void)in_sizes; (void)n_in; (void)out_size; (void)ws_size;

    const float* X  = (const float*)d_in[0];   // (32, 96, 512)
    const float* W1 = (const float*)d_in[1];   // (512, 1024)
    const float* b1 = (const float*)d_in[2];   // (512,)
    const float* W2 = (const float*)d_in[3];   // (1, 512)
    const float* b2 = (const float*)d_in[4];   // (1,)
    float* out = (float*)d_out;                // (32, 96, 96)

    char* ws = (char*)d_ws;
    _Float16* Ea = (_Float16*)(ws);                // 3,145,728 B
    _Float16* Eh = (_Float16*)(ws + 3145728);      // 3,145,728 B
    int* cnt     = (int*)(ws + 6291456);           // 32 ints

    hipMemsetAsync(cnt, 0, 32 * sizeof(int), stream);
    fused_pc<<<512, 256, 0, stream>>>(X, W1, b1, W2, b2, Ea, Eh, cnt, out);
}

// Round 19
// 48.238 us; speedup vs baseline: 2.5908x; 2.5422x over previous
//
#include <hip/hip_runtime.h>
#include <hip/hip_bf16.h>

#define NN 96
// tanh(x) = 1 - 2/(exp2(C*x)+1), C = 2*log2(e)
#define C_TANH 2.8853900817779268f

typedef __attribute__((ext_vector_type(4))) float        f32x4;
typedef __attribute__((ext_vector_type(8))) short        short8;
typedef __attribute__((ext_vector_type(8))) _Float16     half8;
typedef __attribute__((ext_vector_type(4))) unsigned int u32x4;

static __device__ inline unsigned int cvt_pk_bf16(float lo, float hi) {
    unsigned int r;
    asm("v_cvt_pk_bf16_f32 %0, %1, %2" : "=v"(r) : "v"(lo), "v"(hi));
    return r;
}

// L1-bypass (sc0) 16B load: reads the XCD-local L2 directly -- no L1 stale
// risk, no cache-maintenance op. (ext_vector binds to 'v'; structs don't.)
static __device__ inline u32x4 load_b128_glc(const void* p) {
    u32x4 d;
    asm volatile("global_load_dwordx4 %0, %1, off sc0"
                 : "=v"(d) : "v"((unsigned long long)p) : "memory");
    return d;
}

// ===========================================================================
// Single fused producer-consumer kernel. 512 blocks x 256 thr, 48KB LDS +
// launch_bounds(256,3) -> 3 blocks/CU capacity >= grid/256 => co-resident,
// spins terminate.
//
// Coherence design (R16 proved logic correct but 124us of cache-maintenance
// idle; R18's sc1-to-MALL raced the L2-resident flags): ALL blocks touching
// batch b share bid&7 -> same XCD under round-robin dispatch -> ONE L2 is
// the single meeting point. Plain stores land dirty in that L2 (L1 is
// write-through); vmcnt(0)+barrier ACKs them at L2 BEFORE the relaxed
// atomicAdd to the same L2; consumers poll relaxed (no buffer_inv) and read
// data with sc0 loads (L1 bypass) from the same L2. Zero wbl2/inv anywhere.
// If dispatch mapping is not bid&7 round-robin, absmax catches it.
// ===========================================================================
__global__ __launch_bounds__(256, 3) void fused_pc(
        const float* __restrict__ X, const float* __restrict__ W1,
        const float* __restrict__ b1, const float* __restrict__ w2,
        const float* __restrict__ b2, _Float16* __restrict__ Ea,
        _Float16* __restrict__ Eh, int* __restrict__ cnt,
        float* __restrict__ out) {
    __shared__ __align__(16) char smem[49152];

    int bid = blockIdx.x;                // 512 = 8 xcd * 64
    int tid = threadIdx.x;
    int xcd = bid & 7;
    int sub = bid >> 3;                  // 0..63
    int b   = 4 * xcd + (sub >> 4);      // batch 0..31 (batch -> fixed xcd)
    int nq  = sub & 15;                  // gemm n-quarter 0..15
    int w   = tid >> 6;
    int l   = tid & 63;

    bool isB = (nq >= 8);
    int colbase = (nq & 7) * 64;

    // ---------------- producer: gemm 96x64, k-step 64 ----------------
    {
        unsigned short* lds = (unsigned short*)smem;   // [2][160*64] halves

        // staging: 1280 16B-chunks per k-step (rows 0..95 = A, 96..159 = B);
        // 5 chunks/thread. chunk c: row=c>>3, g=c&7; slot = g ^ (row&7).
        const float* src[5];
        int dst[5];
#pragma unroll
        for (int p = 0; p < 5; ++p) {
            int c   = tid + p * 256;
            int row = c >> 3, g = c & 7;
            dst[p] = row * 64 + (g ^ (row & 7)) * 8;
            if (row < 96) {
                src[p] = X + (b * 96 + row) * 512 + g * 8;
            } else {
                int n = nq * 64 + (row - 96);
                src[p] = W1 + (n & 511) * 1024 + ((n >> 9) << 9) + g * 8;
            }
        }

        f32x4 RL[5][2];
#define LOADR(k0)                                                             \
        { _Pragma("unroll")                                                   \
          for (int p = 0; p < 5; ++p) {                                       \
              RL[p][0] = *(const f32x4*)(src[p] + (k0));                      \
              RL[p][1] = *(const f32x4*)(src[p] + (k0) + 4);                  \
          } }
#define WRITER(buf)                                                           \
        { _Pragma("unroll")                                                   \
          for (int p = 0; p < 5; ++p) {                                       \
              u32x4 u;                                                        \
              u.x = cvt_pk_bf16(RL[p][0][0], RL[p][0][1]);                    \
              u.y = cvt_pk_bf16(RL[p][0][2], RL[p][0][3]);                    \
              u.z = cvt_pk_bf16(RL[p][1][0], RL[p][1][1]);                    \
              u.w = cvt_pk_bf16(RL[p][1][2], RL[p][1][3]);                    \
              *(u32x4*)(lds + (buf) * 10240 + dst[p]) = u;                    \
          } }

        f32x4 acc[6] = {};
        int lr = l & 15;
        int kh = l >> 4;                 // 0..3 -> koff = kh*8

#define COMPUTE(buf)                                                          \
        { const unsigned short* base = lds + (buf) * 10240;                   \
          _Pragma("unroll")                                                   \
          for (int kk = 0; kk < 2; ++kk) {                                    \
              int kc = kk * 4 + kh;                                           \
              int rb = 96 + 16 * w + lr;                                      \
              short8 bfr = *(const short8*)(base + rb * 64 + ((kc ^ (rb & 7)) * 8)); \
              _Pragma("unroll")                                               \
              for (int rf = 0; rf < 6; ++rf) {                                \
                  int ra = 16 * rf + lr;                                      \
                  short8 afr = *(const short8*)(base + ra * 64 + ((kc ^ (ra & 7)) * 8)); \
                  acc[rf] = __builtin_amdgcn_mfma_f32_16x16x32_bf16(          \
                      afr, bfr, acc[rf], 0, 0, 0);                            \
              } } }

        LOADR(0)
        WRITER(0)
        __syncthreads();
#pragma unroll 1
        for (int k = 0; k < 7; ++k) {
            LOADR((k + 1) * 64)
            COMPUTE(k & 1)
            WRITER((k + 1) & 1)
            __syncthreads();
        }
        COMPUTE(1)
#undef LOADR
#undef WRITER
#undef COMPUTE

        // epilogue via LDS bounce (12KB in buf0 region, disjoint from buf1
        // which COMPUTE(1) just read). D lane l -> row (l>>4)*4+q, col 16w+lr.
        unsigned short* eb = (unsigned short*)smem;   // [96][64] halves
        int r0   = (l >> 4) * 4;
        int colt = 16 * w + lr;
        float bias = isB ? b1[colbase + colt] : 0.0f;
#pragma unroll
        for (int rf = 0; rf < 6; ++rf)
#pragma unroll
            for (int q = 0; q < 4; ++q) {
                int mrow = 16 * rf + r0 + q;
                float arg = (acc[rf][q] + bias) * C_TANH;
                _Float16 h = (_Float16)exp2f(arg);
                eb[mrow * 64 + colt] = __builtin_bit_cast(unsigned short, h);
            }
        __syncthreads();

        // coalesced PLAIN stores (write-through to the XCD-local L2):
        // 768 x 16B chunks, 3 per thread.
        _Float16* dstp = isB ? Eh : Ea;
#pragma unroll
        for (int p = 0; p < 3; ++p) {
            int idx  = tid + p * 256;
            int mrow = idx >> 3, ch = idx & 7;
            u32x4 v = *(const u32x4*)(eb + mrow * 64 + ch * 8);
            *(u32x4*)(dstp + (b * 96 + mrow) * 512 + colbase + ch * 8) = v;
        }
    }

    // release at the L2: drain this wave's stores (ACKed by L2), barrier so
    // all waves' stores are drained, then RELAXED add to the SAME L2.
    asm volatile("s_waitcnt vmcnt(0)" ::: "memory");
    __syncthreads();
    if (tid == 0)
        __hip_atomic_fetch_add(&cnt[b], 1, __ATOMIC_RELAXED,
                               __HIP_MEMORY_SCOPE_AGENT);

    // spin: RELAXED polls (no buffer_inv), bounded so a logic error fails
    // absmax instead of hanging the container.
    if (tid == 0) {
        int guard = 1 << 22;
        while (--guard &&
               __hip_atomic_load(&cnt[b], __ATOMIC_RELAXED,
                                 __HIP_MEMORY_SCOPE_AGENT) < 16)
            __builtin_amdgcn_s_sleep(8);
    }
    __syncthreads();
    asm volatile("" ::: "memory");       // no load hoisting above the spin

    // ---------------- consumer: arc 24i x 24j ----------------
    {
        _Float16* a_s = (_Float16*)smem;                 // 24x512 = 24KB
        _Float16* h_s = (_Float16*)(smem + 24576);       // 24x512 = 24KB

        int rem = sub & 15;
        int it  = rem >> 2;              // 0..3
        int jt  = rem & 3;               // 0..3

        const _Float16* asrc = Ea + (b * NN + it * 24) * 512;
        const _Float16* hsrc = Eh + (b * NN + jt * 24) * 512;

        // stage via sc0 loads (L1 bypass -> same-XCD L2 dirty lines):
        // issue 12, one waitcnt, 12 LDS writes.
        u32x4 ra[6], rh[6];
#pragma unroll
        for (int p = 0; p < 6; ++p) {
            int idx = tid + p * 256;
            int row = idx >> 6, c = idx & 63;
            ra[p] = load_b128_glc(asrc + row * 512 + c * 8);
            rh[p] = load_b128_glc(hsrc + row * 512 + c * 8);
        }
        asm volatile("s_waitcnt vmcnt(0)" ::: "memory");
#pragma unroll
        for (int p = 0; p < 6; ++p) {
            int idx = tid + p * 256;
            int row = idx >> 6, c = idx & 63, cs = c ^ (row & 7);
            *(u32x4*)(a_s + row * 512 + cs * 8) = ra[p];
            *(u32x4*)(h_s + row * 512 + cs * 8) = rh[p];
        }
        __syncthreads();

        int kq = __builtin_amdgcn_readfirstlane(w);   // SGPR 0..3
        int pi = l >> 3;                 // rows 3pi..3pi+2
        int pj = l & 7;                  // cols 3pj..3pj+2
        const float* wp = w2 + kq * 128; // uniform -> s_load

        const _Float16* pa[3];
        const _Float16* ph[3];
        int sa[3], sh[3];
#pragma unroll
        for (int d = 0; d < 3; ++d) {
            int ra2 = 3 * pi + d;
            int rh2 = 3 * pj + d;
            pa[d] = a_s + ra2 * 512 + kq * 128;
            ph[d] = h_s + rh2 * 512 + kq * 128;
            sa[d] = ra2 & 7;
            sh[d] = rh2 & 7;
        }

        float acc[3][3] = {};

#define FPROC(av, hv, a)                                                      \
        {                                                                     \
            float s0 = __builtin_fmaf((float)av[0], (float)hv[0], 1.0f);      \
            float s1 = __builtin_fmaf((float)av[1], (float)hv[1], 1.0f);      \
            float s2 = __builtin_fmaf((float)av[2], (float)hv[2], 1.0f);      \
            float s3 = __builtin_fmaf((float)av[3], (float)hv[3], 1.0f);      \
            float s4 = __builtin_fmaf((float)av[4], (float)hv[4], 1.0f);      \
            float s5 = __builtin_fmaf((float)av[5], (float)hv[5], 1.0f);      \
            float s6 = __builtin_fmaf((float)av[6], (float)hv[6], 1.0f);      \
            float s7 = __builtin_fmaf((float)av[7], (float)hv[7], 1.0f);      \
            float n0 = __builtin_fmaf(wv1, s0, wv0 * s1);                     \
            float n1 = __builtin_fmaf(wv3, s2, wv2 * s3);                     \
            float n2 = __builtin_fmaf(wv5, s4, wv4 * s5);                     \
            float n3 = __builtin_fmaf(wv7, s6, wv6 * s7);                     \
            a = __builtin_fmaf(n0, __builtin_amdgcn_rcpf(s0 * s1), a);        \
            a = __builtin_fmaf(n1, __builtin_amdgcn_rcpf(s2 * s3), a);        \
            a = __builtin_fmaf(n2, __builtin_amdgcn_rcpf(s4 * s5), a);        \
            a = __builtin_fmaf(n3, __builtin_amdgcn_rcpf(s6 * s7), a);        \
        }

#pragma unroll 2
        for (int c0 = 0; c0 < 16; ++c0) {
            half8 av[3], hv[3];
#pragma unroll
            for (int d = 0; d < 3; ++d) {
                av[d] = *(const half8*)(pa[d] + ((c0 ^ sa[d]) << 3));
                hv[d] = *(const half8*)(ph[d] + ((c0 ^ sh[d]) << 3));
            }
            f32x4 wlo = *(const f32x4*)(wp + c0 * 8);
            f32x4 whi = *(const f32x4*)(wp + c0 * 8 + 4);
            float wv0 = wlo[0], wv1 = wlo[1], wv2 = wlo[2], wv3 = wlo[3];
            float wv4 = whi[0], wv5 = whi[1], wv6 = whi[2], wv7 = whi[3];
#pragma unroll
            for (int di = 0; di < 3; ++di)
#pragma unroll
                for (int dj = 0; dj < 3; ++dj)
                    FPROC(av[di], hv[dj], acc[di][dj])
        }
#undef FPROC

        // cross-wave reduce; red aliases a_s (k-loop reads are done)
        float* red = (float*)smem;       // [2][64][9] = 4608 B
        __syncthreads();
        if (w >= 2) {
            float* rp = red + ((w - 2) * 64 + l) * 9;
#pragma unroll
            for (int di = 0; di < 3; ++di)
#pragma unroll
                for (int dj = 0; dj < 3; ++dj)
                    rp[di * 3 + dj] = acc[di][dj];
        }
        __syncthreads();
        if (w < 2) {
            const float* rp = red + (w * 64 + l) * 9;
#pragma unroll
            for (int di = 0; di < 3; ++di)
#pragma unroll
                for (int dj = 0; dj < 3; ++dj)
                    acc[di][dj] += rp[di * 3 + dj];
        }
        __syncthreads();
        if (w == 1) {
            float* rp = red + l * 9;
#pragma unroll
            for (int di = 0; di < 3; ++di)
#pragma unroll
                for (int dj = 0; dj < 3; ++dj)
                    rp[di * 3 + dj] = acc[di][dj];
        }
        __syncthreads();

        if (w == 0) {
            const float* rp = red + l * 9;
#pragma unroll
            for (int di = 0; di < 3; ++di)
#pragma unroll
                for (int dj = 0; dj < 3; ++dj)
                    acc[di][dj] += rp[di * 3 + dj];

            // S = b2 + sum(w2)
            f32x4 v0 = *(const f32x4*)(w2 + l * 8);
            f32x4 v1 = *(const f32x4*)(w2 + l * 8 + 4);
            float sv = (v0[0] + v0[1]) + (v0[2] + v0[3])
                     + (v1[0] + v1[1]) + (v1[2] + v1[3]);
#pragma unroll
            for (int off = 32; off; off >>= 1) sv += __shfl_xor(sv, off, 64);
            float Sv = sv + b2[0];

#pragma unroll
            for (int di = 0; di < 3; ++di) {
                int i = it * 24 + 3 * pi + di;
                float* op = out + (b * NN + i) * NN + jt * 24 + 3 * pj;
#pragma unroll
                for (int dj = 0; dj < 3; ++dj)
                    op[dj] = __builtin_fmaf(-2.f, acc[di][dj], Sv);
            }
        }
    }
}

// ---------------------------------------------------------------------------
extern "C" void kernel_launch(void* const* d_in, const int* in_sizes, int n_in,
                              void* d_out, int out_size, void* d_ws, size_t ws_size,
                              hipStream_t stream) {
    (void)in_sizes; (void)n_in; (void)out_size; (void)ws_size;

    const float* X  = (const float*)d_in[0];   // (32, 96, 512)
    const float* W1 = (const float*)d_in[1];   // (512, 1024)
    const float* b1 = (const float*)d_in[2];   // (512,)
    const float* W2 = (const float*)d_in[3];   // (1, 512)
    const float* b2 = (const float*)d_in[4];   // (1,)
    float* out = (float*)d_out;                // (32, 96, 96)

    char* ws = (char*)d_ws;
    _Float16* Ea = (_Float16*)(ws);                // 3,145,728 B
    _Float16* Eh = (_Float16*)(ws + 3145728);      // 3,145,728 B
    int* cnt     = (int*)(ws + 6291456);           // 32 ints

    (void)hipMemsetAsync(cnt, 0, 32 * sizeof(int), stream);
    fused_pc<<<512, 256, 0, stream>>>(X, W1, b1, W2, b2, Ea, Eh, cnt, out);
}